// Round 12
// baseline (531.218 us; speedup 1.0000x reference)
//
#include <hip/hip_runtime.h>
#include <math.h>

#define H      128
#define LNUM   5
#define ONUM   5
#define BATCH  16
#define NPTS   50000
#define WPTS   32       // points per wave (= per block; 64-thread blocks, fully wave-autonomous)
#define XROW   152      // halfs per strip row: 128+24 pad

#define K2LOG2E 2.8853900817779268f   // 2*log2(e): tanh arg -> exp2 arg

typedef _Float16      half8    __attribute__((ext_vector_type(8)));
typedef float         floatx4  __attribute__((ext_vector_type(4)));
typedef unsigned int  uint2v   __attribute__((ext_vector_type(2)));
typedef unsigned int  uint4v   __attribute__((ext_vector_type(4)));
typedef unsigned short ushort8_t __attribute__((ext_vector_type(8)));

// wave-private LDS write->read ordering: drain own DS queue. NOT a barrier
// (no s_barrier -- no cross-wave semantics; R9's race was s_barrier misuse).
#define WAVE_LDS_FENCE() asm volatile("s_waitcnt lgkmcnt(0)" ::: "memory")

static __device__ __forceinline__ unsigned short f2h(float f) {
    _Float16 h = (_Float16)f;                       // v_cvt_f16_f32 (RNE)
    return __builtin_bit_cast(unsigned short, h);
}
static __device__ __forceinline__ unsigned int packh(float a, float b) {
    return (unsigned int)f2h(a) | ((unsigned int)f2h(b) << 16);   // RNE pair
}

// ============ fused branch + weight fold: grid (16, 6), 512 thr (unchanged, known-good) ============
__global__ __launch_bounds__(512)
void fold_kernel(const float* __restrict__ params,
                 const float* __restrict__ bW0, const float* __restrict__ bb0,
                 const float* __restrict__ bWh, const float* __restrict__ bbh,
                 const float* __restrict__ balpha,
                 const float* __restrict__ bWf, const float* __restrict__ bbf,
                 const float* __restrict__ tW0, const float* __restrict__ tb0,
                 const float* __restrict__ tWh, const float* __restrict__ tbh,
                 const float* __restrict__ tWf, const float* __restrict__ talpha,
                 const float* __restrict__ tbf,
                 unsigned short* __restrict__ w0s, unsigned short* __restrict__ whs,
                 unsigned short* __restrict__ wcomb, float* __restrict__ bcomb,
                 float* __restrict__ binit) {
    const int b = blockIdx.x, l = blockIdx.y, t = threadIdx.x;
    __shared__ float hbuf[H];
    __shared__ float Sneed[H];
    __shared__ float pbuf[8];
    __shared__ float zl_sh[ONUM][H];
    if (t < 8) pbuf[t] = params[b * 8 + t];
    __syncthreads();

    float scum = 0.0f;
    if (t < H) {
        float acc = bb0[t];
        for (int k = 0; k < 8; ++k) acc += pbuf[k] * bW0[k * H + t];
        float h = balpha[t] * tanhf(acc);
        hbuf[t] = h;
        scum = h;
        if (l == 0) Sneed[t] = scum;
    }
    for (int i = 1; i < LNUM; ++i) {
        __syncthreads();
        float hn = 0.0f;
        if (t < H) {
            const float* Wl = bWh + (i - 1) * H * H;
            float a2 = bbh[(i - 1) * H + t];
            for (int k = 0; k < H; ++k) a2 += hbuf[k] * Wl[k * H + t];
            hn = balpha[i * H + t] * tanhf(a2);
        }
        __syncthreads();
        if (t < H) {
            hbuf[t] = hn;
            scum += hn;
            if (i == l) Sneed[t] = scum;
        }
    }
    __syncthreads();

    if (l == 5) {
        for (int idx = t; idx < ONUM * H; idx += 512) {
            int o = idx >> 7, hh = idx & 127;
            float z = bbf[o * H + hh];
            for (int k = 0; k < H; ++k) z += hbuf[k] * bWf[k * (H * ONUM) + o * H + hh];
            zl_sh[o][hh] = z;
        }
        __syncthreads();
        for (int j = t; j < 16 * H; j += 512) {
            int o = j >> 7, f = j & 127;
            float v = 0.0f;
            if (o < ONUM) {
                const float* wfr = tWf + f * H;
                float s = 0.0f;
                for (int h = 0; h < H; ++h) s += wfr[h] * zl_sh[o][h];
                v = talpha[4 * H + f] * s;
            }
            wcomb[b * 16 * H + j] = f2h(v);
        }
        if (t < 16) {
            float v = 0.0f;
            if (t < ONUM)
                for (int h = 0; h < H; ++h) v += tbf[h] * zl_sh[t][h];
            bcomb[b * 16 + t] = v;
        }
    } else if (l == 0) {
        if (t < H) binit[(b * LNUM + 0) * H + t] = K2LOG2E * Sneed[t] * tb0[t];
        unsigned int* dst = (unsigned int*)(w0s + b * H * 32);
        for (int j = t; j < H * 16; j += 512) {
            int f = j >> 4, k0 = (j & 15) << 1;
            float s = K2LOG2E * Sneed[f];
            float v0 = (k0 < 3)     ? s * tW0[k0 * H + f]       : 0.0f;
            float v1 = (k0 + 1 < 3) ? s * tW0[(k0 + 1) * H + f] : 0.0f;
            dst[j] = packh(v0, v1);
        }
    } else {
        if (t < H) binit[(b * LNUM + l) * H + t] = K2LOG2E * Sneed[t] * tbh[(l - 1) * H + t];
        const float* Wsrc = tWh + (l - 1) * H * H;
        unsigned int* dst = (unsigned int*)(whs + (b * 4 + (l - 1)) * H * H);
        for (int j = t; j < H * H / 2; j += 512) {
            int f = j >> 6, k0 = (j & 63) << 1;
            float s = K2LOG2E * Sneed[f];
            dst[j] = packh(s * Wsrc[k0 * H + f] * talpha[(l - 1) * H + k0],
                           s * Wsrc[(k0 + 1) * H + f] * talpha[(l - 1) * H + k0 + 1]);
        }
    }
}

// ============ trunk: ONE wave per block, 32 pts x ALL 128 feats, ZERO barriers ============
// acc[8][2] = 64 AGPR. Wave-private LDS strip for the D->B layout round-trip;
// same-wave ordering via lgkmcnt only. No __syncthreads anywhere -> no phase
// lockstep, A-frag loads pipeline freely across layers.
// launch_bounds(64,3): 170-reg unified budget (64 AGPR + ~105 VGPR fits; R3/R5
// proved the 128 budget of 4 waves/EU spills this tile class).
__global__ __launch_bounds__(64, 3)
void trunk_kernel(const float* __restrict__ coords,
                  const unsigned short* __restrict__ w0s,
                  const unsigned short* __restrict__ whs,
                  const float* __restrict__ binit,
                  const unsigned short* __restrict__ wcomb,
                  const float* __restrict__ bcomb,
                  float* __restrict__ out) {
    const int b    = blockIdx.y;
    const int n0   = blockIdx.x * WPTS;
    const int lane = threadIdx.x;     // 0..63 (one wave)
    const int q    = lane >> 4;       // quad 0..3
    const int c    = lane & 15;

    __shared__ unsigned short xs[WPTS * XROW];   // 9728 B, private to this block's single wave

    // ---- stage this wave's 32 coords into strip rows (fp16, zero-padded K=32) ----
    int valid = NPTS - n0; if (valid > WPTS) valid = WPTS;
    {
        int p = lane >> 1, hh = lane & 1;
        uint4v z = {0, 0, 0, 0};
        if (hh == 0) {
            float c0 = 0.f, c1 = 0.f, c2 = 0.f;
            if (p < valid) {
                const float* cp = coords + ((size_t)b * NPTS + n0 + p) * 3;
                c0 = cp[0]; c1 = cp[1]; c2 = cp[2];
            }
            z.x = __builtin_bit_cast(unsigned int, __builtin_amdgcn_cvt_pkrtz(c0, c1));
            z.y = __builtin_bit_cast(unsigned int, __builtin_amdgcn_cvt_pkrtz(c2, 0.0f));
            *(uint4v*)&xs[p * XROW + 0] = z;                 // k 0..7
            uint4v zz = {0, 0, 0, 0};
            *(uint4v*)&xs[p * XROW + 16] = zz;               // k 16..23
        } else {
            *(uint4v*)&xs[p * XROW + 8]  = z;                // k 8..15 (z is zero here)
            *(uint4v*)&xs[p * XROW + 24] = z;                // k 24..31
        }
    }
    WAVE_LDS_FENCE();

    floatx4 acc[8][2];

    // ================= layer 0: coords (K=32, folded W0), bias via C-operand =================
    {
        const unsigned short* w0b = w0s + b * H * 32;
        half8 bfr[2];
        #pragma unroll
        for (int nt = 0; nt < 2; ++nt)
            bfr[nt] = __builtin_bit_cast(half8,
                *(const ushort8_t*)&xs[(nt * 16 + c) * XROW + q * 8]);
        #pragma unroll
        for (int mt = 0; mt < 8; ++mt) {
            floatx4 bi4 = *(const floatx4*)&binit[(b * LNUM + 0) * H + mt * 16 + q * 4];
            half8 af = __builtin_bit_cast(half8,
                *(const ushort8_t*)&w0b[(mt * 16 + c) * 32 + q * 8]);
            #pragma unroll
            for (int nt = 0; nt < 2; ++nt)
                acc[mt][nt] = __builtin_amdgcn_mfma_f32_16x16x32_f16(af, bfr[nt], bi4, 0, 0, 0);
        }
    }
    // ---- epilogue layer 0 -> strip (wave-private; fence before reads) ----
    #pragma unroll
    for (int mt = 0; mt < 8; ++mt) {
        int f0 = mt * 16 + q * 4;
        #pragma unroll
        for (int nt = 0; nt < 2; ++nt) {
            int pt = nt * 16 + c;
            floatx4 v = acc[mt][nt];
            #pragma unroll
            for (int r = 0; r < 4; ++r) {
                float e  = __builtin_amdgcn_exp2f(v[r]);     // acc = 2log2e*S*(Wx+b)
                float rc = __builtin_amdgcn_rcpf(e + 1.0f);
                v[r] = __builtin_fmaf(-2.0f, rc, 1.0f);      // tanh
            }
            uint2v u;
            u.x = __builtin_bit_cast(unsigned int, __builtin_amdgcn_cvt_pkrtz(v[0], v[1]));
            u.y = __builtin_bit_cast(unsigned int, __builtin_amdgcn_cvt_pkrtz(v[2], v[3]));
            *(uint2v*)&xs[pt * XROW + f0] = u;
        }
    }
    WAVE_LDS_FENCE();

    // ================= hidden layers 1..4 (folded Wh) =================
    for (int l = 1; l <= 4; ++l) {
        const unsigned short* wl = whs + (b * 4 + (l - 1)) * H * H;
        #pragma unroll
        for (int mt = 0; mt < 8; ++mt) {
            floatx4 bi4 = *(const floatx4*)&binit[(b * LNUM + l) * H + mt * 16 + q * 4];
            #pragma unroll
            for (int nt = 0; nt < 2; ++nt) acc[mt][nt] = bi4;
        }
        #pragma unroll
        for (int s = 0; s < 4; ++s) {
            half8 bfr[2];
            #pragma unroll
            for (int nt = 0; nt < 2; ++nt)
                bfr[nt] = __builtin_bit_cast(half8,
                    *(const ushort8_t*)&xs[(nt * 16 + c) * XROW + s * 32 + q * 8]);
            #pragma unroll
            for (int mt = 0; mt < 8; ++mt) {
                half8 af = __builtin_bit_cast(half8,
                    *(const ushort8_t*)&wl[(mt * 16 + c) * H + s * 32 + q * 8]);
                #pragma unroll
                for (int nt = 0; nt < 2; ++nt)
                    acc[mt][nt] = __builtin_amdgcn_mfma_f32_16x16x32_f16(af, bfr[nt], acc[mt][nt], 0, 0, 0);
            }
        }
        WAVE_LDS_FENCE();                         // strip reads done before overwrite
        #pragma unroll
        for (int mt = 0; mt < 8; ++mt) {
            int f0 = mt * 16 + q * 4;
            #pragma unroll
            for (int nt = 0; nt < 2; ++nt) {
                int pt = nt * 16 + c;
                floatx4 v = acc[mt][nt];
                #pragma unroll
                for (int r = 0; r < 4; ++r) {
                    float e  = __builtin_amdgcn_exp2f(v[r]);
                    float rc = __builtin_amdgcn_rcpf(e + 1.0f);
                    v[r] = __builtin_fmaf(-2.0f, rc, 1.0f);
                }
                uint2v u;
                u.x = __builtin_bit_cast(unsigned int, __builtin_amdgcn_cvt_pkrtz(v[0], v[1]));
                u.y = __builtin_bit_cast(unsigned int, __builtin_amdgcn_cvt_pkrtz(v[2], v[3]));
                *(uint2v*)&xs[pt * XROW + f0] = u;
            }
        }
        WAVE_LDS_FENCE();                         // strip writes visible to next layer's reads
    }

    // ---- collapsed layer5+einsum: out[b,pt,o] = x4[pt,:] @ Wcomb[o,:] + bcomb[o] ----
    {
        floatx4 bc = *(const floatx4*)&bcomb[b * 16 + q * 4];
        floatx4 oacc[2] = {bc, bc};
        const unsigned short* wc = wcomb + b * 16 * H;
        #pragma unroll
        for (int s = 0; s < 4; ++s) {
            half8 af = __builtin_bit_cast(half8,
                *(const ushort8_t*)&wc[c * H + s * 32 + q * 8]);
            #pragma unroll
            for (int nt = 0; nt < 2; ++nt) {
                half8 bfr = __builtin_bit_cast(half8,
                    *(const ushort8_t*)&xs[(nt * 16 + c) * XROW + s * 32 + q * 8]);
                oacc[nt] = __builtin_amdgcn_mfma_f32_16x16x32_f16(af, bfr, oacc[nt], 0, 0, 0);
            }
        }
        #pragma unroll
        for (int nt = 0; nt < 2; ++nt) {
            int pt = n0 + nt * 16 + c;
            if (pt < NPTS) {
                float* op = out + ((size_t)b * NPTS + pt) * ONUM;
                if (q == 0) {
                    op[0] = oacc[nt][0]; op[1] = oacc[nt][1];
                    op[2] = oacc[nt][2]; op[3] = oacc[nt][3];
                } else if (q == 1) {
                    op[4] = oacc[nt][0];
                }
            }
        }
    }
}

extern "C" void kernel_launch(void* const* d_in, const int* in_sizes, int n_in,
                              void* d_out, int out_size, void* d_ws, size_t ws_size,
                              hipStream_t stream) {
    const float* coords       = (const float*)d_in[0];
    const float* params       = (const float*)d_in[1];
    const float* branch_W0    = (const float*)d_in[2];
    const float* branch_b0    = (const float*)d_in[3];
    const float* branch_Wh    = (const float*)d_in[4];
    const float* branch_bh    = (const float*)d_in[5];
    const float* branch_alpha = (const float*)d_in[6];
    const float* branch_Wf    = (const float*)d_in[7];
    const float* branch_bf    = (const float*)d_in[8];
    const float* trunk_W0     = (const float*)d_in[9];
    const float* trunk_b0     = (const float*)d_in[10];
    const float* trunk_Wh     = (const float*)d_in[11];
    const float* trunk_bh     = (const float*)d_in[12];
    const float* trunk_alpha  = (const float*)d_in[13];
    const float* trunk_Wf     = (const float*)d_in[14];
    const float* trunk_bf     = (const float*)d_in[15];
    float* out = (float*)d_out;

    // workspace layout (256B-aligned offsets)
    char* ws = (char*)d_ws;
    float*          binit = (float*)(ws + 0);                 // 16*5*128 f32   = 40960
    unsigned short* wcomb = (unsigned short*)(ws + 40960);    // 16*16*128 f16  = 65536
    float*          bcomb = (float*)(ws + 106496);            // 16*16 f32      = 1024
    unsigned short* w0s   = (unsigned short*)(ws + 107520);   // 16*128*32 f16  = 131072
    unsigned short* whs   = (unsigned short*)(ws + 238592);   // 16*4*128*128   = 2097152
    // end: 2335744 B

    fold_kernel<<<dim3(BATCH, 6), 512, 0, stream>>>(params, branch_W0, branch_b0,
                                                    branch_Wh, branch_bh, branch_alpha,
                                                    branch_Wf, branch_bf,
                                                    trunk_W0, trunk_b0, trunk_Wh, trunk_bh,
                                                    trunk_Wf, trunk_alpha, trunk_bf,
                                                    w0s, whs, wcomb, bcomb, binit);
    trunk_kernel<<<dim3((NPTS + WPTS - 1) / WPTS, BATCH), 64, 0, stream>>>(
        coords, w0s, whs, binit, wcomb, bcomb, out);
}

// Round 13
// 283.900 us; speedup vs baseline: 1.8711x; 1.8711x over previous
//
#include <hip/hip_runtime.h>
#include <math.h>

#define H      128
#define LNUM   5
#define ONUM   5
#define BATCH  16
#define NPTS   50000
#define TP     128      // points per trunk block (4 waves x 32-feat slices)
#define XROW   152      // halfs per xs row: 128+24 pad

#define K2LOG2E 2.8853900817779268f   // 2*log2(e): tanh arg -> exp2 arg

typedef _Float16      half8    __attribute__((ext_vector_type(8)));
typedef float         floatx4  __attribute__((ext_vector_type(4)));
typedef unsigned int  uint2v   __attribute__((ext_vector_type(2)));
typedef unsigned int  uint4v   __attribute__((ext_vector_type(4)));
typedef unsigned short ushort8_t __attribute__((ext_vector_type(8)));

static __device__ __forceinline__ unsigned short f2h(float f) {
    _Float16 h = (_Float16)f;                       // v_cvt_f16_f32 (RNE)
    return __builtin_bit_cast(unsigned short, h);
}
static __device__ __forceinline__ unsigned int packh(float a, float b) {
    return (unsigned int)f2h(a) | ((unsigned int)f2h(b) << 16);   // RNE pair
}

// ============ fused branch + weight fold: grid (16, 6), 512 thr (unchanged, known-good) ============
__global__ __launch_bounds__(512)
void fold_kernel(const float* __restrict__ params,
                 const float* __restrict__ bW0, const float* __restrict__ bb0,
                 const float* __restrict__ bWh, const float* __restrict__ bbh,
                 const float* __restrict__ balpha,
                 const float* __restrict__ bWf, const float* __restrict__ bbf,
                 const float* __restrict__ tW0, const float* __restrict__ tb0,
                 const float* __restrict__ tWh, const float* __restrict__ tbh,
                 const float* __restrict__ tWf, const float* __restrict__ talpha,
                 const float* __restrict__ tbf,
                 unsigned short* __restrict__ w0s, unsigned short* __restrict__ whs,
                 unsigned short* __restrict__ wcomb, float* __restrict__ bcomb,
                 float* __restrict__ binit) {
    const int b = blockIdx.x, l = blockIdx.y, t = threadIdx.x;
    __shared__ float hbuf[H];
    __shared__ float Sneed[H];
    __shared__ float pbuf[8];
    __shared__ float zl_sh[ONUM][H];
    if (t < 8) pbuf[t] = params[b * 8 + t];
    __syncthreads();

    float scum = 0.0f;
    if (t < H) {
        float acc = bb0[t];
        for (int k = 0; k < 8; ++k) acc += pbuf[k] * bW0[k * H + t];
        float h = balpha[t] * tanhf(acc);
        hbuf[t] = h;
        scum = h;
        if (l == 0) Sneed[t] = scum;
    }
    for (int i = 1; i < LNUM; ++i) {
        __syncthreads();
        float hn = 0.0f;
        if (t < H) {
            const float* Wl = bWh + (i - 1) * H * H;
            float a2 = bbh[(i - 1) * H + t];
            for (int k = 0; k < H; ++k) a2 += hbuf[k] * Wl[k * H + t];
            hn = balpha[i * H + t] * tanhf(a2);
        }
        __syncthreads();
        if (t < H) {
            hbuf[t] = hn;
            scum += hn;
            if (i == l) Sneed[t] = scum;
        }
    }
    __syncthreads();

    if (l == 5) {
        for (int idx = t; idx < ONUM * H; idx += 512) {
            int o = idx >> 7, hh = idx & 127;
            float z = bbf[o * H + hh];
            for (int k = 0; k < H; ++k) z += hbuf[k] * bWf[k * (H * ONUM) + o * H + hh];
            zl_sh[o][hh] = z;
        }
        __syncthreads();
        for (int j = t; j < 16 * H; j += 512) {
            int o = j >> 7, f = j & 127;
            float v = 0.0f;
            if (o < ONUM) {
                const float* wfr = tWf + f * H;
                float s = 0.0f;
                for (int h = 0; h < H; ++h) s += wfr[h] * zl_sh[o][h];
                v = talpha[4 * H + f] * s;
            }
            wcomb[b * 16 * H + j] = f2h(v);
        }
        if (t < 16) {
            float v = 0.0f;
            if (t < ONUM)
                for (int h = 0; h < H; ++h) v += tbf[h] * zl_sh[t][h];
            bcomb[b * 16 + t] = v;
        }
    } else if (l == 0) {
        if (t < H) binit[(b * LNUM + 0) * H + t] = K2LOG2E * Sneed[t] * tb0[t];
        unsigned int* dst = (unsigned int*)(w0s + b * H * 32);
        for (int j = t; j < H * 16; j += 512) {
            int f = j >> 4, k0 = (j & 15) << 1;
            float s = K2LOG2E * Sneed[f];
            float v0 = (k0 < 3)     ? s * tW0[k0 * H + f]       : 0.0f;
            float v1 = (k0 + 1 < 3) ? s * tW0[(k0 + 1) * H + f] : 0.0f;
            dst[j] = packh(v0, v1);
        }
    } else {
        if (t < H) binit[(b * LNUM + l) * H + t] = K2LOG2E * Sneed[t] * tbh[(l - 1) * H + t];
        const float* Wsrc = tWh + (l - 1) * H * H;
        unsigned int* dst = (unsigned int*)(whs + (b * 4 + (l - 1)) * H * H);
        for (int j = t; j < H * H / 2; j += 512) {
            int f = j >> 6, k0 = (j & 63) << 1;
            float s = K2LOG2E * Sneed[f];
            dst[j] = packh(s * Wsrc[k0 * H + f] * talpha[(l - 1) * H + k0],
                           s * Wsrc[(k0 + 1) * H + f] * talpha[(l - 1) * H + k0 + 1]);
        }
    }
}

// ============ trunk: 128 points/block, 4 waves, wave tile = 32 feats x 128 pts ============
// acc[2][8] = 64 AGPR; unified ~155 fits the 170-reg budget of 3 waves/EU.
// (64-AGPR tiles spill at the 128 budget of 4 waves/EU -- R3/R5.)
// TP=128 halves per-point weight loads (0.25/pt) and per-point barrier cost vs R8.
// ALL barriers are __syncthreads (R9: hand-rolled s_barrier raced).
__global__ __launch_bounds__(256, 3)
void trunk_kernel(const float* __restrict__ coords,
                  const unsigned short* __restrict__ w0s,
                  const unsigned short* __restrict__ whs,
                  const float* __restrict__ binit,
                  const unsigned short* __restrict__ wcomb,
                  const float* __restrict__ bcomb,
                  float* __restrict__ out) {
    const int b    = blockIdx.y;
    const int n0   = blockIdx.x * TP;
    const int tid  = threadIdx.x;
    const int lane = tid & 63;
    const int w    = tid >> 6;        // wave 0..3
    const int q    = lane >> 4;       // quad 0..3
    const int c    = lane & 15;
    const int mq   = w * 32;          // wave's feature quarter (M); every wave covers all 128 pts

    __shared__ unsigned short xs[TP * XROW];   // 38912 B -> 3 blocks/CU (VGPR-bound)

    // ---- stage coords into xs[p][0..31] (fp16, zero-padded K) ----
    int valid = NPTS - n0; if (valid > TP) valid = TP;
    {
        int p = tid >> 1, hh = tid & 1;
        if (hh == 0) {
            float c0 = 0.f, c1 = 0.f, c2 = 0.f;
            if (p < valid) {
                const float* cp = coords + ((size_t)b * NPTS + n0 + p) * 3;
                c0 = cp[0]; c1 = cp[1]; c2 = cp[2];
            }
            uint4v z;
            z.x = __builtin_bit_cast(unsigned int, __builtin_amdgcn_cvt_pkrtz(c0, c1));
            z.y = __builtin_bit_cast(unsigned int, __builtin_amdgcn_cvt_pkrtz(c2, 0.0f));
            z.z = 0; z.w = 0;
            *(uint4v*)&xs[p * XROW + 0] = z;                 // k 0..7
            uint4v zz = {0, 0, 0, 0};
            *(uint4v*)&xs[p * XROW + 8] = zz;                // k 8..15
        } else {
            uint4v zz = {0, 0, 0, 0};
            *(uint4v*)&xs[p * XROW + 16] = zz;               // k 16..31
            *(uint4v*)&xs[p * XROW + 24] = zz;
        }
    }
    __syncthreads();

    floatx4 acc[2][8];

    // ================= layer 0: coords (K=32, folded W0), bias via C-operand =================
    #pragma unroll
    for (int mt = 0; mt < 2; ++mt) {
        floatx4 bi4 = *(const floatx4*)&binit[(b * LNUM + 0) * H + mq + mt * 16 + q * 4];
        #pragma unroll
        for (int nt = 0; nt < 8; ++nt) acc[mt][nt] = bi4;
    }
    {
        const unsigned short* w0b = w0s + b * H * 32;
        half8 af[2];
        #pragma unroll
        for (int mt = 0; mt < 2; ++mt)
            af[mt] = __builtin_bit_cast(half8,
                *(const ushort8_t*)&w0b[(mq + mt * 16 + c) * 32 + q * 8]);
        #pragma unroll
        for (int nt = 0; nt < 8; ++nt) {
            half8 bfr = __builtin_bit_cast(half8,
                *(const ushort8_t*)&xs[(nt * 16 + c) * XROW + q * 8]);
            #pragma unroll
            for (int mt = 0; mt < 2; ++mt)
                acc[mt][nt] = __builtin_amdgcn_mfma_f32_16x16x32_f16(af[mt], bfr, acc[mt][nt], 0, 0, 0);
        }
    }
    __syncthreads();
    // ---- epilogue layer 0: acc already = 2log2e*S*(Wx+b) ----
    #pragma unroll
    for (int mt = 0; mt < 2; ++mt) {
        int f0 = mq + mt * 16 + q * 4;
        #pragma unroll
        for (int nt = 0; nt < 8; ++nt) {
            int pt = nt * 16 + c;
            floatx4 v = acc[mt][nt];
            #pragma unroll
            for (int r = 0; r < 4; ++r) {
                float e  = __builtin_amdgcn_exp2f(v[r]);
                float rc = __builtin_amdgcn_rcpf(e + 1.0f);
                v[r] = __builtin_fmaf(-2.0f, rc, 1.0f);             // tanh
            }
            uint2v u;
            u.x = __builtin_bit_cast(unsigned int, __builtin_amdgcn_cvt_pkrtz(v[0], v[1]));
            u.y = __builtin_bit_cast(unsigned int, __builtin_amdgcn_cvt_pkrtz(v[2], v[3]));
            *(uint2v*)&xs[pt * XROW + f0] = u;
        }
    }

    // ================= hidden layers 1..4 (folded Wh) =================
    for (int l = 1; l <= 4; ++l) {
        const unsigned short* wl = whs + (b * 4 + (l - 1)) * H * H;
        #pragma unroll
        for (int mt = 0; mt < 2; ++mt) {
            floatx4 bi4 = *(const floatx4*)&binit[(b * LNUM + l) * H + mq + mt * 16 + q * 4];
            #pragma unroll
            for (int nt = 0; nt < 8; ++nt) acc[mt][nt] = bi4;
        }
        __syncthreads();                          // prev epilogue writes visible
        #pragma unroll
        for (int s = 0; s < 4; ++s) {
            half8 af[2];
            #pragma unroll
            for (int mt = 0; mt < 2; ++mt)
                af[mt] = __builtin_bit_cast(half8,
                    *(const ushort8_t*)&wl[(mq + mt * 16 + c) * H + s * 32 + q * 8]);
            #pragma unroll
            for (int nt = 0; nt < 8; ++nt) {
                half8 bfr = __builtin_bit_cast(half8,
                    *(const ushort8_t*)&xs[(nt * 16 + c) * XROW + s * 32 + q * 8]);
                #pragma unroll
                for (int mt = 0; mt < 2; ++mt)
                    acc[mt][nt] = __builtin_amdgcn_mfma_f32_16x16x32_f16(af[mt], bfr, acc[mt][nt], 0, 0, 0);
            }
        }
        __syncthreads();                          // all xs reads done before overwrite
        #pragma unroll
        for (int mt = 0; mt < 2; ++mt) {
            int f0 = mq + mt * 16 + q * 4;
            #pragma unroll
            for (int nt = 0; nt < 8; ++nt) {
                int pt = nt * 16 + c;
                floatx4 v = acc[mt][nt];
                #pragma unroll
                for (int r = 0; r < 4; ++r) {
                    float e  = __builtin_amdgcn_exp2f(v[r]);
                    float rc = __builtin_amdgcn_rcpf(e + 1.0f);
                    v[r] = __builtin_fmaf(-2.0f, rc, 1.0f);
                }
                uint2v u;
                u.x = __builtin_bit_cast(unsigned int, __builtin_amdgcn_cvt_pkrtz(v[0], v[1]));
                u.y = __builtin_bit_cast(unsigned int, __builtin_amdgcn_cvt_pkrtz(v[2], v[3]));
                *(uint2v*)&xs[pt * XROW + f0] = u;
            }
        }
    }
    __syncthreads();                              // x4 (tanh) ready in xs

    // ---- collapsed layer5+einsum: out[b,pt,o] = x4[pt,:] @ Wcomb[o,:] + bcomb[o] ----
    // wave w handles pts [32w, 32w+32)
    {
        floatx4 bc = *(const floatx4*)&bcomb[b * 16 + q * 4];
        floatx4 oacc[2] = {bc, bc};
        const unsigned short* wc = wcomb + b * 16 * H;
        #pragma unroll
        for (int s = 0; s < 4; ++s) {
            half8 af = __builtin_bit_cast(half8,
                *(const ushort8_t*)&wc[c * H + s * 32 + q * 8]);
            #pragma unroll
            for (int nt = 0; nt < 2; ++nt) {
                half8 bfr = __builtin_bit_cast(half8,
                    *(const ushort8_t*)&xs[(w * 32 + nt * 16 + c) * XROW + s * 32 + q * 8]);
                oacc[nt] = __builtin_amdgcn_mfma_f32_16x16x32_f16(af, bfr, oacc[nt], 0, 0, 0);
            }
        }
        #pragma unroll
        for (int nt = 0; nt < 2; ++nt) {
            int pt = n0 + w * 32 + nt * 16 + c;
            if (pt < NPTS) {
                float* op = out + ((size_t)b * NPTS + pt) * ONUM;
                if (q == 0) {
                    op[0] = oacc[nt][0]; op[1] = oacc[nt][1];
                    op[2] = oacc[nt][2]; op[3] = oacc[nt][3];
                } else if (q == 1) {
                    op[4] = oacc[nt][0];
                }
            }
        }
    }
}

extern "C" void kernel_launch(void* const* d_in, const int* in_sizes, int n_in,
                              void* d_out, int out_size, void* d_ws, size_t ws_size,
                              hipStream_t stream) {
    const float* coords       = (const float*)d_in[0];
    const float* params       = (const float*)d_in[1];
    const float* branch_W0    = (const float*)d_in[2];
    const float* branch_b0    = (const float*)d_in[3];
    const float* branch_Wh    = (const float*)d_in[4];
    const float* branch_bh    = (const float*)d_in[5];
    const float* branch_alpha = (const float*)d_in[6];
    const float* branch_Wf    = (const float*)d_in[7];
    const float* branch_bf    = (const float*)d_in[8];
    const float* trunk_W0     = (const float*)d_in[9];
    const float* trunk_b0     = (const float*)d_in[10];
    const float* trunk_Wh     = (const float*)d_in[11];
    const float* trunk_bh     = (const float*)d_in[12];
    const float* trunk_alpha  = (const float*)d_in[13];
    const float* trunk_Wf     = (const float*)d_in[14];
    const float* trunk_bf     = (const float*)d_in[15];
    float* out = (float*)d_out;

    // workspace layout (256B-aligned offsets)
    char* ws = (char*)d_ws;
    float*          binit = (float*)(ws + 0);                 // 16*5*128 f32   = 40960
    unsigned short* wcomb = (unsigned short*)(ws + 40960);    // 16*16*128 f16  = 65536
    float*          bcomb = (float*)(ws + 106496);            // 16*16 f32      = 1024
    unsigned short* w0s   = (unsigned short*)(ws + 107520);   // 16*128*32 f16  = 131072
    unsigned short* whs   = (unsigned short*)(ws + 238592);   // 16*4*128*128   = 2097152
    // end: 2335744 B

    fold_kernel<<<dim3(BATCH, 6), 512, 0, stream>>>(params, branch_W0, branch_b0,
                                                    branch_Wh, branch_bh, branch_alpha,
                                                    branch_Wf, branch_bf,
                                                    trunk_W0, trunk_b0, trunk_Wh, trunk_bh,
                                                    trunk_Wf, trunk_alpha, trunk_bf,
                                                    w0s, whs, wcomb, bcomb, binit);
    trunk_kernel<<<dim3((NPTS + TP - 1) / TP, BATCH), 256, 0, stream>>>(
        coords, w0s, whs, binit, wcomb, bcomb, out);
}